// Round 4
// baseline (17.980 us; speedup 1.0000x reference)
//
#include <hip/hip_runtime.h>

// LengthRegulator LR path (fused single kernel):
//   x: [B, T_IN, H] fp32, duration: [B, T_MEL] int (0 => zero frame, 1..T_IN => x[d-1])
//   out0: [B, T_MEL, H] fp32 gather;  out1: mel_len[B] = first zero index else T_MEL (fp32)
// B=16, T_IN=512, H=256, T_MEL=4096

#define H_DIM 256
#define T_IN  512
#define T_MEL 4096
#define TPB 256
#define F4_PER_BLOCK 2048   // 8 iters * 256 threads * 1 float4 = 32 rows/block

typedef float f32x4 __attribute__((ext_vector_type(4)));

__global__ __launch_bounds__(TPB) void lr_fused_kernel(
    const float* __restrict__ x, const int* __restrict__ dur,
    float* __restrict__ out, float* __restrict__ mel_out,
    int nB, int nblk) {

    // ---- fused mel_len: blocks 0..nB-1 scan their batch's 16 KB dur row ----
    if ((int)blockIdx.x < nB) {
        const int b = blockIdx.x;
        const int4* row = reinterpret_cast<const int4*>(dur + (size_t)b * T_MEL);
        int m = T_MEL;
        #pragma unroll
        for (int i = 0; i < T_MEL / 4 / TPB; ++i) {
            const int idx = i * TPB + threadIdx.x;
            const int4 dv = row[idx];
            const int t = idx << 2;
            if (dv.x == 0) m = min(m, t);
            if (dv.y == 0) m = min(m, t + 1);
            if (dv.z == 0) m = min(m, t + 2);
            if (dv.w == 0) m = min(m, t + 3);
        }
        for (int off = 32; off > 0; off >>= 1)
            m = min(m, __shfl_down(m, off, 64));
        __shared__ int sm[TPB / 64];
        if ((threadIdx.x & 63) == 0) sm[threadIdx.x >> 6] = m;
        __syncthreads();
        if (threadIdx.x == 0)
            mel_out[b] = (float)min(min(sm[0], sm[1]), min(sm[2], sm[3]));
    }

    // ---- gather: XCD-chunked (bijective: nblk % 8 == 0) ----
    const int eff  = ((int)blockIdx.x & 7) * (nblk >> 3) + ((int)blockIdx.x >> 3);
    const int row0 = eff << 5;            // 32 consecutive rows per block
    const int b    = row0 >> 12;          // whole block inside ONE batch (4096 rows/batch)
    const float* __restrict__ xb = x + (size_t)b * (T_IN * H_DIM);  // block-uniform
    const int wid  = threadIdx.x >> 6;
    const int lane = threadIdx.x & 63;

    // batch all 8 dur loads (wave-uniform address per iteration -> broadcast)
    int d[8];
    #pragma unroll
    for (int i = 0; i < 8; ++i)
        d[i] = dur[row0 + i * 4 + wid];

    // branchless x loads (d==0 -> load row 0, select zero after; ~0.2% waste)
    f32x4 v[8];
    #pragma unroll
    for (int i = 0; i < 8; ++i) {
        const int dd = d[i] ? d[i] - 1 : 0;
        const f32x4 t = *reinterpret_cast<const f32x4*>(
            xb + (size_t)dd * H_DIM + lane * 4);
        const f32x4 z = {0.f, 0.f, 0.f, 0.f};
        v[i] = d[i] ? t : z;
    }

    // regular cached stores: L2 write-combining sustains ~6.5 TB/s (fill kernel evidence)
    f32x4* __restrict__ o4 = reinterpret_cast<f32x4*>(out) + ((size_t)row0 << 6);
    #pragma unroll
    for (int i = 0; i < 8; ++i)
        o4[i * TPB + threadIdx.x] = v[i];
}

extern "C" void kernel_launch(void* const* d_in, const int* in_sizes, int n_in,
                              void* d_out, int out_size, void* d_ws, size_t ws_size,
                              hipStream_t stream) {
    const float* x   = (const float*)d_in[0];
    const int*   dur = (const int*)d_in[1];
    float* out = (float*)d_out;

    const int n_dur = in_sizes[1];                 // B * T_MEL
    const int B     = n_dur / T_MEL;               // 16
    const long long rows   = n_dur;                // 65536
    const long long n_vec4 = rows * (H_DIM / 4);   // 4,194,304 float4
    const int nblk = (int)(n_vec4 / F4_PER_BLOCK); // 2048 (exact)

    float* mel_out = out + (size_t)rows * H_DIM;   // tail: B fp32 values

    lr_fused_kernel<<<nblk, TPB, 0, stream>>>(x, dur, out, mel_out, B, nblk);
}

// Round 5
// 17.798 us; speedup vs baseline: 1.0102x; 1.0102x over previous
//
#include <hip/hip_runtime.h>

// LengthRegulator LR path (fused single kernel):
//   x: [B, T_IN, H] fp32, duration: [B, T_MEL] int (0 => zero frame, 1..T_IN => x[d-1])
//   out0: [B, T_MEL, H] fp32 gather;  out1: mel_len[B] = first zero index else T_MEL (fp32)
// B=16, T_IN=512, H=256, T_MEL=4096

#define H_DIM 256
#define T_IN  512
#define T_MEL 4096
#define TPB 256
#define F4_PER_BLOCK 2048   // 8 iters * 256 threads * 1 float4 = 32 rows/block

typedef float f32x4 __attribute__((ext_vector_type(4)));

__global__ __launch_bounds__(TPB) void lr_fused_kernel(
    const float* __restrict__ x, const int* __restrict__ dur,
    float* __restrict__ out, float* __restrict__ mel_out,
    int nB, int nblk) {

    // ---- fused mel_len: blocks 0..nB-1 scan their batch's 16 KB dur row ----
    if ((int)blockIdx.x < nB) {
        const int b = blockIdx.x;
        const int4* row = reinterpret_cast<const int4*>(dur + (size_t)b * T_MEL);
        int m = T_MEL;
        #pragma unroll
        for (int i = 0; i < T_MEL / 4 / TPB; ++i) {
            const int idx = i * TPB + threadIdx.x;
            const int4 dv = row[idx];
            const int t = idx << 2;
            if (dv.x == 0) m = min(m, t);
            if (dv.y == 0) m = min(m, t + 1);
            if (dv.z == 0) m = min(m, t + 2);
            if (dv.w == 0) m = min(m, t + 3);
        }
        for (int off = 32; off > 0; off >>= 1)
            m = min(m, __shfl_down(m, off, 64));
        __shared__ int sm[TPB / 64];
        if ((threadIdx.x & 63) == 0) sm[threadIdx.x >> 6] = m;
        __syncthreads();
        if (threadIdx.x == 0)
            mel_out[b] = (float)min(min(sm[0], sm[1]), min(sm[2], sm[3]));
    }

    // ---- gather: XCD-chunked (bijective: nblk % 8 == 0) ----
    const int eff  = ((int)blockIdx.x & 7) * (nblk >> 3) + ((int)blockIdx.x >> 3);
    const int row0 = eff << 5;            // 32 consecutive rows per block
    const int b    = row0 >> 12;          // whole block inside ONE batch (4096 rows/batch)
    const float* __restrict__ xb = x + (size_t)b * (T_IN * H_DIM);  // block-uniform
    const int wid  = threadIdx.x >> 6;    // wave-uniform
    const int lane = threadIdx.x & 63;

    // batch all 8 dur loads; index is wave-uniform -> broadcast transaction
    int d[8];
    #pragma unroll
    for (int i = 0; i < 8; ++i)
        d[i] = dur[row0 + i * 4 + wid];

    // Force d into SGPRs: gather row is wave-uniform, so the x row base is a
    // SCALAR. All 8 loads then share one VGPR offset (lane*16) with SGPR bases
    // -> shorter VALU chain, fewer VGPRs.
    f32x4 v[8];
    #pragma unroll
    for (int i = 0; i < 8; ++i) {
        const int sd = __builtin_amdgcn_readfirstlane(d[i]);
        const int dd = sd ? sd - 1 : 0;
        const f32x4 t = *reinterpret_cast<const f32x4*>(
            xb + (size_t)dd * H_DIM + lane * 4);
        const f32x4 z = {0.f, 0.f, 0.f, 0.f};
        v[i] = sd ? t : z;
    }

    f32x4* __restrict__ o4 = reinterpret_cast<f32x4*>(out) + ((size_t)row0 << 6);
    #pragma unroll
    for (int i = 0; i < 8; ++i)
        o4[i * TPB + threadIdx.x] = v[i];
}

extern "C" void kernel_launch(void* const* d_in, const int* in_sizes, int n_in,
                              void* d_out, int out_size, void* d_ws, size_t ws_size,
                              hipStream_t stream) {
    const float* x   = (const float*)d_in[0];
    const int*   dur = (const int*)d_in[1];
    float* out = (float*)d_out;

    const int n_dur = in_sizes[1];                 // B * T_MEL
    const int B     = n_dur / T_MEL;               // 16
    const long long rows   = n_dur;                // 65536
    const long long n_vec4 = rows * (H_DIM / 4);   // 4,194,304 float4
    const int nblk = (int)(n_vec4 / F4_PER_BLOCK); // 2048 (exact)

    float* mel_out = out + (size_t)rows * H_DIM;   // tail: B fp32 values

    lr_fused_kernel<<<nblk, TPB, 0, stream>>>(x, dur, out, mel_out, B, nblk);
}